// Round 8
// baseline (180.603 us; speedup 1.0000x reference)
//
#include <hip/hip_runtime.h>
#include <stdint.h>

#define KK 5
#define BS 8
#define NCH8 64        // uint4 bp blocks per batch (T/8)
#define PITCH 41       // LDS row pitch in dwords (41%32=9, odd -> free 2-way)
#define DPITCH 516     // decode staging row bytes

struct TBlk { int4 lo, hi; };
__device__ __forceinline__ int telt(const TBlk& tb, int s) {   // s compile-time
  const int4 v = (s < 4) ? tb.lo : tb.hi;
  const int m = s & 3;
  return m == 0 ? v.x : (m == 1 ? v.y : (m == 2 ? v.z : v.w));
}
__device__ __forceinline__ float sel5(float v0, float v1, float v2, float v3,
                                      float v4, int ct) {
  float u = v0;
  u = (ct == 1) ? v1 : u;
  u = (ct == 2) ? v2 : u;
  u = (ct == 3) ? v3 : u;
  u = (ct == 4) ? v4 : u;
  return u;
}

// coalesced chunk load: 64 batches x 8 steps x 5 floats = 640 float4, 10/lane
__device__ __forceinline__ void loadC(float4 (&S)[10], const float* __restrict__ potg,
                                      const int (&goffd)[10], int c) {
#pragma unroll
  for (int j = 0; j < 10; ++j)
    S[j] = *(const float4*)(potg + goffd[j] + c * 40);
}

// ---------------- Viterbi: one 8-step chunk, writes of NEXT chunk interleaved
__device__ __forceinline__ void vit_chunk8(const float* __restrict__ rb,
    float* __restrict__ wb, bool wr, const float4 (&S)[10], const int (&loffd)[10],
    int c, int len, int lane, const float (&tr)[KK][KK], float (&a)[KK],
    uint4* __restrict__ bpp) {
  uint32_t w[4] = {0u, 0u, 0u, 0u};
#pragma unroll
  for (int s = 0; s < BS; ++s) {
    const int base = lane * PITCH + s * 5;
    const float v0 = rb[base], v1 = rb[base + 1], v2 = rb[base + 2],
                v3 = rb[base + 3], v4 = rb[base + 4];
    if (wr) {                      // 5 staged ds_writes per step (off-chain)
#pragma unroll
      for (int w2 = 5 * s; w2 < 5 * s + 5; ++w2) {
        const int j = w2 >> 2, q = w2 & 3;
        const float4 sv = S[j];
        wb[loffd[j] + q] = (q == 0 ? sv.x : q == 1 ? sv.y : q == 2 ? sv.z : sv.w);
      }
    }
    const int t = c * BS + s;
    if (c == 0 && s == 0) {
      a[0] = v0; a[1] = v1; a[2] = v2; a[3] = v3; a[4] = v4;
    } else {
      const bool act = (t < len);
      float nv[KK];
      uint32_t bits = 0;
#pragma unroll
      for (int j = 0; j < KK; ++j) {
        const float s0 = a[0] + tr[0][j];
        const float s1 = a[1] + tr[1][j];
        const float s2 = a[2] + tr[2][j];
        const float s3 = a[3] + tr[3][j];
        const float s4 = a[4] + tr[4][j];
        const float bm = fmaxf(fmaxf(fmaxf(s0, s1), fmaxf(s2, s3)), s4);
        int bi = 4;                // first-max tie-break == jnp.argmax
        bi = (s3 == bm) ? 3 : bi;
        bi = (s2 == bm) ? 2 : bi;
        bi = (s1 == bm) ? 1 : bi;
        bi = (s0 == bm) ? 0 : bi;
        const float pj = (j == 0) ? v0 : (j == 1) ? v1 : (j == 2) ? v2 : (j == 3) ? v3 : v4;
        nv[j] = bm + pj;
        bits |= (uint32_t)bi << (3 * j);
      }
      if (act) {
#pragma unroll
        for (int j = 0; j < KK; ++j) a[j] = nv[j];
        w[s >> 1] |= bits << ((s & 1) << 4);
      }
    }
  }
  if (c * BS < len) bpp[c] = make_uint4(w[0], w[1], w[2], w[3]);
}

// ---------------- forward + score: one 8-step chunk ----------------
__device__ __forceinline__ void fwd_chunk8(const float* __restrict__ rb,
    float* __restrict__ wb, bool wr, const float4 (&S)[10], const int (&loffd)[10],
    int c, int len, int lane, const float (&W)[KK][KK],
    const float* __restrict__ s_trans, const TBlk& TB,
    float (&p)[KK], float& Cacc, float& unary, float& binary, int& pt) {
#pragma unroll
  for (int s = 0; s < BS; ++s) {
    const int base = lane * PITCH + s * 5;
    const float v0 = rb[base], v1 = rb[base + 1], v2 = rb[base + 2],
                v3 = rb[base + 3], v4 = rb[base + 4];
    if (wr) {
#pragma unroll
      for (int w2 = 5 * s; w2 < 5 * s + 5; ++w2) {
        const int j = w2 >> 2, q = w2 & 3;
        const float4 sv = S[j];
        wb[loffd[j] + q] = (q == 0 ? sv.x : q == 1 ? sv.y : q == 2 ? sv.z : sv.w);
      }
    }
    const int t = c * BS + s;
    if (c == 0 && s == 0) {
      p[0] = __expf(v0); p[1] = __expf(v1); p[2] = __expf(v2);
      p[3] = __expf(v3); p[4] = __expf(v4);
      pt = telt(TB, 0);
      unary = sel5(v0, v1, v2, v3, v4, pt);
    } else {
      const bool act = (t < len);
      const float E0 = __expf(v0), E1 = __expf(v1), E2 = __expf(v2),
                  E3 = __expf(v3), E4 = __expf(v4);
      float np_[KK];
      {
        float a0 = p[0] * W[0][0]; a0 = fmaf(p[1], W[1][0], a0); a0 = fmaf(p[2], W[2][0], a0); a0 = fmaf(p[3], W[3][0], a0); a0 = fmaf(p[4], W[4][0], a0); np_[0] = a0 * E0;
        float a1 = p[0] * W[0][1]; a1 = fmaf(p[1], W[1][1], a1); a1 = fmaf(p[2], W[2][1], a1); a1 = fmaf(p[3], W[3][1], a1); a1 = fmaf(p[4], W[4][1], a1); np_[1] = a1 * E1;
        float a2 = p[0] * W[0][2]; a2 = fmaf(p[1], W[1][2], a2); a2 = fmaf(p[2], W[2][2], a2); a2 = fmaf(p[3], W[3][2], a2); a2 = fmaf(p[4], W[4][2], a2); np_[2] = a2 * E2;
        float a3 = p[0] * W[0][3]; a3 = fmaf(p[1], W[1][3], a3); a3 = fmaf(p[2], W[2][3], a3); a3 = fmaf(p[3], W[3][3], a3); a3 = fmaf(p[4], W[4][3], a3); np_[3] = a3 * E3;
        float a4 = p[0] * W[0][4]; a4 = fmaf(p[1], W[1][4], a4); a4 = fmaf(p[2], W[2][4], a4); a4 = fmaf(p[3], W[3][4], a4); a4 = fmaf(p[4], W[4][4], a4); np_[4] = a4 * E4;
      }
      const int ct = telt(TB, s);
      const float u = sel5(v0, v1, v2, v3, v4, ct);
      const float bnr = s_trans[pt * KK + ct];
      if (act) {
#pragma unroll
        for (int j = 0; j < KK; ++j) p[j] = np_[j];
        unary += u;
        binary += bnr;
        pt = ct;
      }
    }
  }
  // renorm once per 8 steps (representation-neutral; safe for frozen lanes)
  const float m = fmaxf(fmaxf(fmaxf(p[0], p[1]), fmaxf(p[2], p[3])), p[4]);
  const float r = 1.0f / m;
#pragma unroll
  for (int j = 0; j < KK; ++j) p[j] *= r;
  Cacc += __logf(m);
}

// ---------------------------------------------------------------------------
// 2*(B/64) blocks x 64 threads, ONE wave per block, zero barriers.
// Thread-per-batch compute (pure-VALU chain). Coalesced global->reg staging,
// double-buffered (S0/S1, full-chunk lead); reg->LDS writes spread 5/step so
// LDS reads never queue behind a write burst. role 0 = Viterbi, role 1 =
// forward+score; blocks g and g+128 share batches and XCD (128%8==0).
// ---------------------------------------------------------------------------
__launch_bounds__(64)
__global__ void crf_kernel(const float* __restrict__ pot,
                           const float* __restrict__ trans,
                           const int* __restrict__ lens,
                           const int* __restrict__ tags,
                           float* __restrict__ out,
                           uint4* __restrict__ bp4,
                           int B, int T) {
  __shared__ float sb2[2][64 * PITCH];      // 21 KB staging, double-buffered
  __shared__ uint8_t s_dec[64 * DPITCH];    // 33 KB decode staging (V only)
  __shared__ float s_trans[KK * KK];
  const int lane = threadIdx.x;
  const int ngrp = B / 64;                  // 128
  const int role = (blockIdx.x >= ngrp) ? 1 : 0;
  const int grp = blockIdx.x - role * ngrp;
  const int bbase = grp * 64;
  const int b = bbase + lane;
  const int len = lens[b];
  const int tk = T * KK;                    // 2560
  const float* __restrict__ potg = pot + (size_t)bbase * tk;

  if (lane < KK * KK) s_trans[lane] = trans[lane];

  int ml = len;
#pragma unroll
  for (int d = 1; d < 64; d <<= 1) ml = max(ml, __shfl_xor(ml, d));
  const int nch = (ml + BS - 1) / BS;       // wave-uniform chunk count

  // per-lane staging offsets (compile-time-indexed arrays only)
  int goffd[10], loffd[10];
#pragma unroll
  for (int j = 0; j < 10; ++j) {
    const int g = lane + 64 * j;            // 0..639
    const int b_ = g / 10, c4 = g % 10;
    goffd[j] = b_ * tk + c4 * 4;            // dword offset in global
    loffd[j] = b_ * PITCH + c4 * 4;         // dword offset in LDS row layout
  }

  // ---- pipeline prologue: chunk0 -> LDS (one-time stall), chunk1 -> S1 ----
  float4 S0[10], S1[10];
  loadC(S0, potg, goffd, 0);
#pragma unroll
  for (int w2 = 0; w2 < 40; ++w2) {
    const int j = w2 >> 2, q = w2 & 3;
    const float4 sv = S0[j];
    sb2[0][loffd[j] + q] = (q == 0 ? sv.x : q == 1 ? sv.y : q == 2 ? sv.z : sv.w);
  }
  loadC(S1, potg, goffd, min(1, nch - 1));

  if (role == 0) {
    // ========================= Viterbi =========================
    float tr[KK][KK];
#pragma unroll
    for (int i = 0; i < KK; ++i)
#pragma unroll
      for (int j = 0; j < KK; ++j) tr[i][j] = trans[i * KK + j];  // uniform -> s_load
    float a[KK];
    uint4* __restrict__ bpp = bp4 + (size_t)b * NCH8;
    for (int c = 0; c < nch; ++c) {
      if ((c & 1) == 0) {
        if (c + 2 < nch) loadC(S0, potg, goffd, c + 2);
        vit_chunk8(&sb2[0][0], &sb2[1][0], c + 1 < nch, S1, loffd, c, len, lane, tr, a, bpp);
      } else {
        if (c + 2 < nch) loadC(S1, potg, goffd, c + 2);
        vit_chunk8(&sb2[1][0], &sb2[0][0], c + 1 < nch, S0, loffd, c, len, lane, tr, a, bpp);
      }
    }
    // final alpha argmax (first-max)
    const float bm = fmaxf(fmaxf(fmaxf(a[0], a[1]), fmaxf(a[2], a[3])), a[4]);
    int last = 4;
    last = (a[3] == bm) ? 3 : last;
    last = (a[2] == bm) ? 2 : last;
    last = (a[1] == bm) ? 1 : last;
    last = (a[0] == bm) ? 0 : last;

    // ========== backtrace: 6-deep prefetch ring over bp chunks ==========
    s_dec[lane * DPITCH + (len - 1)] = (uint8_t)last;
    int tag = last;
    const uint4* __restrict__ bq = bpp;
    int i = nch - 1;
    uint4 v0 = bq[i];
    uint4 v1 = bq[max(i - 1, 0)];
    uint4 v2 = bq[max(i - 2, 0)];
    uint4 v3 = bq[max(i - 3, 0)];
    uint4 v4 = bq[max(i - 4, 0)];
    uint4 v5 = bq[max(i - 5, 0)];
    while (i >= 0) {
      const int t8 = i * BS;
#pragma unroll
      for (int s = BS - 1; s >= 0; --s) {
        const int t = t8 + s;
        if (t >= 1 && t < len) {
          const uint32_t w = (s >> 1) == 0 ? v0.x : (s >> 1) == 1 ? v0.y
                           : (s >> 1) == 2 ? v0.z : v0.w;
          const int pv = (int)((w >> ((3 * tag) + ((s & 1) << 4))) & 7u);
          s_dec[lane * DPITCH + (t - 1)] = (uint8_t)pv;
          tag = pv;
        }
      }
      v0 = v1; v1 = v2; v2 = v3; v3 = v4; v4 = v5;
      v5 = bq[max(i - 6, 0)];
      --i;
    }
    // ============== coalesced decode flush: LDS u8 -> f32 rows ==============
    for (int r = 0; r < 64; ++r) {
      const int lr = __shfl(len, r);
      const uint8_t* rowp = s_dec + r * DPITCH + lane * 8;
      const uint32_t w0 = *(const uint32_t*)(rowp);
      const uint32_t w1 = *(const uint32_t*)(rowp + 4);
      const int t0 = lane * 8;
      float f[8];
#pragma unroll
      for (int q = 0; q < 8; ++q) {
        const uint32_t byte = ((q < 4 ? w0 >> (8 * q) : w1 >> (8 * (q - 4))) & 0xffu);
        f[q] = (t0 + q < lr) ? (float)byte : 0.0f;
      }
      float* orow = out + (size_t)(bbase + r) * T + t0;
      *(float4*)(orow)     = make_float4(f[0], f[1], f[2], f[3]);
      *(float4*)(orow + 4) = make_float4(f[4], f[5], f[6], f[7]);
    }

  } else {
    // ==================== forward (linear-space) + score ====================
    float W[KK][KK];
#pragma unroll
    for (int i = 0; i < KK; ++i)
#pragma unroll
      for (int j = 0; j < KK; ++j) W[i][j] = __expf(trans[i * KK + j]);
    float p[KK];
    float Cacc = 0.0f, unary = 0.0f, binary = 0.0f;
    int pt = 0;
    const int* __restrict__ tg = tags + (size_t)b * T;
    TBlk T0, T1;
    T0.lo = *(const int4*)(tg);
    T0.hi = *(const int4*)(tg + 4);
    {
      const int o = BS * min(1, nch - 1);
      T1.lo = *(const int4*)(tg + o);
      T1.hi = *(const int4*)(tg + o + 4);
    }
    for (int c = 0; c < nch; ++c) {
      if ((c & 1) == 0) {
        if (c + 2 < nch) loadC(S0, potg, goffd, c + 2);
        fwd_chunk8(&sb2[0][0], &sb2[1][0], c + 1 < nch, S1, loffd, c, len, lane,
                   W, s_trans, T0, p, Cacc, unary, binary, pt);
      } else {
        if (c + 2 < nch) loadC(S1, potg, goffd, c + 2);
        fwd_chunk8(&sb2[1][0], &sb2[0][0], c + 1 < nch, S0, loffd, c, len, lane,
                   W, s_trans, T0, p, Cacc, unary, binary, pt);
      }
      T0 = T1;
      const int o = BS * min(c + 2, nch - 1);
      T1.lo = *(const int4*)(tg + o);
      T1.hi = *(const int4*)(tg + o + 4);
    }
    const float zsum = p[0] + p[1] + p[2] + p[3] + p[4];
    const float logZ = Cacc + __logf(zsum);
    out[(size_t)B * T + b] = unary + binary - logZ;
  }
}

// ---------------------------------------------------------------------------
extern "C" void kernel_launch(void* const* d_in, const int* in_sizes, int n_in,
                              void* d_out, int out_size, void* d_ws, size_t ws_size,
                              hipStream_t stream) {
  const float* pot   = (const float*)d_in[0];
  const float* trans = (const float*)d_in[1];
  const int*   lens  = (const int*)d_in[2];
  const int*   tags  = (const int*)d_in[3];
  float* out = (float*)d_out;

  const int B = in_sizes[2];
  const int T = in_sizes[3] / B;   // 512

  uint4* bp4 = (uint4*)d_ws;       // B * 64 * 16 B = 8 MB backpointer scratch

  crf_kernel<<<2 * (B / 64), 64, 0, stream>>>(pot, trans, lens, tags, out, bp4, B, T);
}

// Round 9
// 133.223 us; speedup vs baseline: 1.3556x; 1.3556x over previous
//
#include <hip/hip_runtime.h>
#include <stdint.h>

#define KK 5
#define TT 512

// ---- quad_perm DPP helpers: cross-lane within 4-lane quads, VALU pipe ----
#define QPC(a,b,c,d) ((a)|((b)<<2)|((c)<<4)|((d)<<6))
template<int C> __device__ __forceinline__ float qpf(float v) {
  return __int_as_float(__builtin_amdgcn_mov_dpp(__float_as_int(v), C, 0xF, 0xF, false));
}
template<int C> __device__ __forceinline__ int qpi(int v) {
  return __builtin_amdgcn_mov_dpp(v, C, 0xF, 0xF, false);
}
#define BB0 QPC(0,0,0,0)
#define BB1 QPC(1,1,1,1)
#define BB2 QPC(2,2,2,2)
#define BB3 QPC(3,3,3,3)
#define SW1 QPC(1,0,3,2)
#define SW2 QPC(2,3,0,1)

#define MAX5(a,b,c,d,e) fmaxf(fmaxf(fmaxf(a,b),fmaxf(c,d)),e)
__device__ __forceinline__ int amax5(float s0,float s1,float s2,float s3,float s4,float bm){
  int bi=4; bi=(s3==bm)?3:bi; bi=(s2==bm)?2:bi; bi=(s1==bm)?1:bi; bi=(s0==bm)?0:bi; return bi;
}
__device__ __forceinline__ uint32_t sel5u(uint32_t w0,uint32_t w1,uint32_t w2,uint32_t w3,uint32_t w4,int ct){
  uint32_t u=w0; u=(ct==1)?w1:u; u=(ct==2)?w2:u; u=(ct==3)?w3:u; u=(ct==4)?w4:u; return u;
}

// 8-step column chunk: lane's own column r and column 4, t = 8k+1 .. 8k+8
__device__ __forceinline__ void loadQ(float (&pv)[8], float (&q4)[8],
                                      const float* __restrict__ prow, int r, int k) {
  const int t0 = k * 8 + 1;
  if (k < TT / 8 - 1) {
#pragma unroll
    for (int s = 0; s < 8; ++s) {
      pv[s] = prow[(t0 + s) * KK + r];
      q4[s] = prow[(t0 + s) * KK + 4];
    }
  } else {
#pragma unroll
    for (int s = 0; s < 8; ++s) {
      const int t = min(t0 + s, TT - 1);
      pv[s] = prow[t * KK + r];
      q4[s] = prow[t * KK + 4];
    }
  }
}

// ---------------- Viterbi: one 8-step chunk (DPP broadcasts, no DS on chain)
__device__ __forceinline__ void vit8(const float (&pv)[8], const float (&q4)[8],
    int k, int len, const float (&trR)[KK], const float (&tr4)[KK],
    float& a, float& a4, float& afR, float& af4,
    int q, int r, uint32_t* __restrict__ s_bits) {
  uint32_t bR = 0, b4 = 0;
#pragma unroll
  for (int s = 0; s < 8; ++s) {
    const int t = k * 8 + s + 1;
    const float av0 = qpf<BB0>(a), av1 = qpf<BB1>(a), av2 = qpf<BB2>(a), av3 = qpf<BB3>(a);
    // own column r
    const float c0 = av0 + trR[0], c1 = av1 + trR[1], c2 = av2 + trR[2],
                c3 = av3 + trR[3], c4 = a4 + trR[4];
    const float bmR = MAX5(c0, c1, c2, c3, c4);
    const int biR = amax5(c0, c1, c2, c3, c4, bmR);
    // column 4 (replicated in all lanes)
    const float u0 = av0 + tr4[0], u1 = av1 + tr4[1], u2 = av2 + tr4[2],
                u3 = av3 + tr4[3], u4 = a4 + tr4[4];
    const float bm4 = MAX5(u0, u1, u2, u3, u4);
    const int bi4 = amax5(u0, u1, u2, u3, u4, bm4);
    const float nR = bmR + pv[s];
    const float n4 = bm4 + q4[s];
    afR = (t == len - 1) ? nR : afR;     // off-chain capture, no freeze
    af4 = (t == len - 1) ? n4 : af4;
    a = nR; a4 = n4;
    bR |= (uint32_t)biR << (3 * s);
    b4 |= (uint32_t)bi4 << (3 * s);
  }
  s_bits[q * 321 + k * 5 + r] = bR;              // 1 ds_write (off-chain)
  if (r == 0) s_bits[q * 321 + k * 5 + 4] = b4;  // predicated ds_write
}

// ---------------- forward: one 8-step chunk (linear space, quad renorm) ----
__device__ __forceinline__ void fwd8(const float (&pv)[8], const float (&q4)[8],
    int k, int len, const float (&WR)[KK], const float (&W4)[KK],
    float& p, float& p4, float& Cacc, float& pfR, float& pf4, float& Cf) {
#pragma unroll
  for (int s = 0; s < 8; ++s) {
    const int t = k * 8 + s + 1;
    const float pv0 = qpf<BB0>(p), pv1 = qpf<BB1>(p), pv2 = qpf<BB2>(p), pv3 = qpf<BB3>(p);
    const float E = __expf(pv[s]), E4 = __expf(q4[s]);
    float aR = pv0 * WR[0];
    aR = fmaf(pv1, WR[1], aR); aR = fmaf(pv2, WR[2], aR);
    aR = fmaf(pv3, WR[3], aR); aR = fmaf(p4, WR[4], aR);
    float a4n = pv0 * W4[0];
    a4n = fmaf(pv1, W4[1], a4n); a4n = fmaf(pv2, W4[2], a4n);
    a4n = fmaf(pv3, W4[3], a4n); a4n = fmaf(p4, W4[4], a4n);
    const float nR = aR * E, n4 = a4n * E4;
    pfR = (t == len - 1) ? nR : pfR;      // pre-renorm captures
    pf4 = (t == len - 1) ? n4 : pf4;
    Cf  = (t == len - 1) ? Cacc : Cf;
    p = nR; p4 = n4;
  }
  // renorm once per chunk (uniform within quad; exact log bookkeeping)
  float m = p;
  m = fmaxf(m, qpf<SW1>(m));
  m = fmaxf(m, qpf<SW2>(m));
  m = fmaxf(m, p4);
  const float ri = 1.0f / m;
  p *= ri; p4 *= ri;
  Cacc += __logf(m);
}

// ---------------------------------------------------------------------------
// grid: 2*(B/16) blocks x 64 threads (1 wave, no barriers). Quad = 1 batch:
// lane r in {0..3} owns alpha[r]; alpha[4] replicated per-quad. All cross-lane
// traffic on the scan chain is quad_perm DPP (VALU). role 0 = Viterbi,
// role 1 = forward+score; blocks g and g+512 share batches and XCD (512%8==0).
// ---------------------------------------------------------------------------
__launch_bounds__(64)
__global__ void crf_kernel(const float* __restrict__ pot,
                           const float* __restrict__ trans,
                           const int* __restrict__ lens,
                           const int* __restrict__ tags,
                           float* __restrict__ out,
                           int B, int T) {
  __shared__ uint32_t s_bits[16 * 321];
  __shared__ uint32_t s_chosen[16 * 65];
  __shared__ float s_trans[KK * KK];
  const int lane = threadIdx.x;
  const int q = lane >> 2, r = lane & 3;
  const int ngrp = B / 16;                  // 512
  const int role = (blockIdx.x >= ngrp) ? 1 : 0;
  const int grp = blockIdx.x - role * ngrp;
  const int b = grp * 16 + q;
  const int len = lens[b];
  const float* __restrict__ prow = pot + (size_t)b * (T * KK);

  if (lane < KK * KK) s_trans[lane] = trans[lane];

  int ml = len;
  ml = max(ml, __shfl_xor(ml, 4));
  ml = max(ml, __shfl_xor(ml, 8));
  ml = max(ml, __shfl_xor(ml, 16));
  ml = max(ml, __shfl_xor(ml, 32));
  const int nblk = (ml + 7) >> 3;           // wave-uniform

  if (role == 0) {
    // ========================= Viterbi =========================
    float trR[KK], tr4[KK];
#pragma unroll
    for (int i = 0; i < KK; ++i) {
      trR[i] = trans[i * KK + r];           // per-lane column
      tr4[i] = trans[i * KK + 4];           // uniform -> scalar
    }
    float a = prow[r], a4 = prow[4];
    float afR = a, af4 = a4;                // covers len==1

    float pA[8], qA[8], pB[8], qB[8], pC[8], qC[8];
    loadQ(pA, qA, prow, r, 0);
    loadQ(pB, qB, prow, r, min(1, nblk - 1));
    loadQ(pC, qC, prow, r, min(2, nblk - 1));
    int blk = 0;
    while (true) {
      vit8(pA, qA, blk, len, trR, tr4, a, a4, afR, af4, q, r, s_bits);
      if (++blk == nblk) break;
      loadQ(pA, qA, prow, r, min(blk + 2, nblk - 1));
      vit8(pB, qB, blk, len, trR, tr4, a, a4, afR, af4, q, r, s_bits);
      if (++blk == nblk) break;
      loadQ(pB, qB, prow, r, min(blk + 2, nblk - 1));
      vit8(pC, qC, blk, len, trR, tr4, a, a4, afR, af4, q, r, s_bits);
      if (++blk == nblk) break;
      loadQ(pC, qC, prow, r, min(blk + 2, nblk - 1));
    }
    // final argmax over 5 (first-max): quad max + replicated col4
    float m = afR;
    m = fmaxf(m, qpf<SW1>(m));
    m = fmaxf(m, qpf<SW2>(m));
    const float bm = fmaxf(m, af4);
    int cand = (afR == bm) ? r : ((af4 == bm) ? 4 : 7);
    cand = min(cand, qpi<SW1>(cand));
    cand = min(cand, qpi<SW2>(cand));
    const int last = cand;

    // ============ post-scan backtrace: lane r==0 per quad ============
    if (r == 0) {
      int tag = last;
      uint32_t acc = (uint32_t)last << (3 * ((len - 1) & 7));
      int kcur = (len - 1) >> 3;
      const uint32_t* __restrict__ bb = s_bits + q * 321;
      int kb = (len - 2) >> 3;               // len==1 -> -1, loop skipped
      uint32_t w0 = 0, w1 = 0, w2 = 0, w3 = 0, w4 = 0;
      if (kb >= 0) {
        w0 = bb[kb * 5 + 0]; w1 = bb[kb * 5 + 1]; w2 = bb[kb * 5 + 2];
        w3 = bb[kb * 5 + 3]; w4 = bb[kb * 5 + 4];
      }
      for (; kb >= 0; --kb) {
        uint32_t n0 = 0, n1 = 0, n2 = 0, n3 = 0, n4 = 0;
        if (kb > 0) {
          n0 = bb[(kb - 1) * 5 + 0]; n1 = bb[(kb - 1) * 5 + 1];
          n2 = bb[(kb - 1) * 5 + 2]; n3 = bb[(kb - 1) * 5 + 3];
          n4 = bb[(kb - 1) * 5 + 4];
        }
#pragma unroll
        for (int s = 7; s >= 0; --s) {
          const int t = kb * 8 + s + 1;      // transition into t; emits pos t-1
          if (t <= len - 1) {
            const uint32_t w = sel5u(w0, w1, w2, w3, w4, tag);
            const int prev = (int)((w >> (3 * s)) & 7u);
            if (kb != kcur) { s_chosen[q * 65 + kcur] = acc; acc = 0; kcur = kb; }
            acc |= (uint32_t)prev << (3 * s);
            tag = prev;
          }
        }
        w0 = n0; w1 = n1; w2 = n2; w3 = n3; w4 = n4;
      }
      s_chosen[q * 65 + kcur] = acc;
    }

    // ============ coalesced decoded write (all lanes) ============
    float* __restrict__ orow = out + (size_t)b * T;
#pragma unroll
    for (int kk = 0; kk < 16; ++kk) {
      const int k2 = kk * 4 + r;
      const uint32_t w = s_chosen[q * 65 + k2];
      const int base = k2 * 8;
      float f[8];
#pragma unroll
      for (int pI = 0; pI < 8; ++pI)
        f[pI] = (base + pI < len) ? (float)((w >> (3 * pI)) & 7u) : 0.0f;
      *(float4*)(orow + base)     = make_float4(f[0], f[1], f[2], f[3]);
      *(float4*)(orow + base + 4) = make_float4(f[4], f[5], f[6], f[7]);
    }

  } else {
    // ==================== forward + score ====================
    float pA[8], qA[8], pB[8], qB[8], pC[8], qC[8];
    loadQ(pA, qA, prow, r, 0);
    loadQ(pB, qB, prow, r, min(1, nblk - 1));
    loadQ(pC, qC, prow, r, min(2, nblk - 1));

    // ---- score prologue: lane r sums t in [r*128, r*128+128) ----
    const int* __restrict__ tgrow = tags + (size_t)b * T;
    float sc = 0.0f;
    {
      const int t0 = r * 128;
      int ptag = (r == 0) ? 0 : tgrow[t0 - 1];
#pragma unroll 4
      for (int qq = 0; qq < 32; ++qq) {
        const int4 tq = *(const int4*)(tgrow + t0 + qq * 4);
#pragma unroll
        for (int mI = 0; mI < 4; ++mI) {
          const int t = t0 + qq * 4 + mI;
          const int ct = (mI == 0) ? tq.x : (mI == 1) ? tq.y : (mI == 2) ? tq.z : tq.w;
          const float uadd = prow[t * KK + ct];
          const float badd = s_trans[ptag * KK + ct];
          const float contrib = uadd + ((t >= 1) ? badd : 0.0f);
          sc += (t < len) ? contrib : 0.0f;
          ptag = ct;
        }
      }
    }
    sc += qpf<SW1>(sc);
    sc += qpf<SW2>(sc);                   // quad total (all lanes hold it)

    // ---- forward scan ----
    float WR[KK], W4[KK];
#pragma unroll
    for (int i = 0; i < KK; ++i) {
      WR[i] = __expf(trans[i * KK + r]);
      W4[i] = __expf(trans[i * KK + 4]);
    }
    float p = __expf(prow[r]), p4 = __expf(prow[4]);
    float Cacc = 0.0f;
    float pfR = p, pf4 = p4, Cf = 0.0f;   // covers len==1

    int blk = 0;
    while (true) {
      fwd8(pA, qA, blk, len, WR, W4, p, p4, Cacc, pfR, pf4, Cf);
      if (++blk == nblk) break;
      loadQ(pA, qA, prow, r, min(blk + 2, nblk - 1));
      fwd8(pB, qB, blk, len, WR, W4, p, p4, Cacc, pfR, pf4, Cf);
      if (++blk == nblk) break;
      loadQ(pB, qB, prow, r, min(blk + 2, nblk - 1));
      fwd8(pC, qC, blk, len, WR, W4, p, p4, Cacc, pfR, pf4, Cf);
      if (++blk == nblk) break;
      loadQ(pC, qC, prow, r, min(blk + 2, nblk - 1));
    }
    float ps = pfR;
    ps += qpf<SW1>(ps);
    ps += qpf<SW2>(ps);                   // quad sum of pf[0..3]
    ps += pf4;                            // col4 added once (replicated)
    const float logZ = Cf + __logf(ps);
    if (r == 0) out[(size_t)B * T + b] = sc - logZ;
  }
}

// ---------------------------------------------------------------------------
extern "C" void kernel_launch(void* const* d_in, const int* in_sizes, int n_in,
                              void* d_out, int out_size, void* d_ws, size_t ws_size,
                              hipStream_t stream) {
  const float* pot   = (const float*)d_in[0];
  const float* trans = (const float*)d_in[1];
  const int*   lens  = (const int*)d_in[2];
  const int*   tags  = (const int*)d_in[3];
  float* out = (float*)d_out;

  const int B = in_sizes[2];
  const int T = in_sizes[3] / B;   // 512

  const int nblocks = 2 * (B / 16);  // 1024
  crf_kernel<<<nblocks, 64, 0, stream>>>(pot, trans, lens, tags, out, B, T);
}

// Round 11
// 121.287 us; speedup vs baseline: 1.4890x; 1.0984x over previous
//
#include <hip/hip_runtime.h>
#include <stdint.h>

#define KK 5
#define TT 512

// ---- cross-lane helpers (8-lane groups; 8 | 32 so groups never straddle the
// ds_swizzle 32-lane boundary) ----
template<int P> __device__ __forceinline__ float swzf(float v) {
  return __int_as_float(__builtin_amdgcn_ds_swizzle(__float_as_int(v), P));
}
template<int P> __device__ __forceinline__ int swzi(int v) {
  return __builtin_amdgcn_ds_swizzle(v, P);
}
// broadcast lane (group*8 + i): offset = (i<<5) | 0x18
#define BC0 0x018
#define BC1 0x038
#define BC2 0x058
#define BC3 0x078
#define BC4 0x098
// xor-butterfly within 8-lane group: offset = (m<<10) | 0x1F
#define X1 0x041F
#define X2 0x081F
#define X4 0x101F

__device__ __forceinline__ float sel5f(float v0,float v1,float v2,float v3,float v4,int ct){
  float u=v0; u=(ct==1)?v1:u; u=(ct==2)?v2:u; u=(ct==3)?v3:u; u=(ct==4)?v4:u; return u;
}
__device__ __forceinline__ uint32_t sel5u(uint32_t w0,uint32_t w1,uint32_t w2,uint32_t w3,uint32_t w4,int ct){
  uint32_t u=w0; u=(ct==1)?w1:u; u=(ct==2)?w2:u; u=(ct==3)?w3:u; u=(ct==4)?w4:u; return u;
}
__device__ __forceinline__ int telt(const int4 (&tp)[2], int s) {   // s compile-time
  const int4 v = (s < 4) ? tp[0] : tp[1];
  const int m = s & 3;
  return m == 0 ? v.x : (m == 1 ? v.y : (m == 2 ? v.z : v.w));
}

// load one 8-step column block: element t for t = 8k+1 .. 8k+8 (clamped)
__device__ __forceinline__ void loadCol(float (&d)[8], const float* __restrict__ colp, int k) {
  const int t0 = k * 8 + 1;
  if (k < TT / 8 - 1) {
#pragma unroll
    for (int s = 0; s < 8; ++s) d[s] = colp[(t0 + s) * KK];
  } else {
#pragma unroll
    for (int s = 0; s < 8; ++s) d[s] = colp[min(t0 + s, TT - 1) * KK];
  }
}
// aligned tag window [8k, 8k+7]
__device__ __forceinline__ void loadTag(int4 (&tp)[2], const int* __restrict__ tg, int k) {
  tp[0] = *(const int4*)(tg + 8 * k);
  tp[1] = *(const int4*)(tg + 8 * k + 4);
}

// ---------------- Viterbi: 8 scan steps + path map + fused score ----------
__device__ __forceinline__ void vit_map_block(const float (&pv)[8], const int4 (&tp)[2],
    int k, int len, int len_eff, const float (&trc)[KK], float& a,
    float& pvcar, int& tagcar, float& usum, float& bsum,
    int jj, int g, int r, uint32_t* __restrict__ s_map) {
  uint32_t bits = 0;
#pragma unroll
  for (int s = 0; s < 8; ++s) {
    const float av0 = swzf<BC0>(a), av1 = swzf<BC1>(a), av2 = swzf<BC2>(a),
                av3 = swzf<BC3>(a), av4 = swzf<BC4>(a);
    const float s0 = av0 + trc[0], s1 = av1 + trc[1], s2 = av2 + trc[2],
                s3 = av3 + trc[3], s4 = av4 + trc[4];
    const float bm = fmaxf(fmaxf(fmaxf(s0, s1), fmaxf(s2, s3)), s4);
    int bi = 4;                      // first-max tie-break == jnp.argmax
    bi = (s3 == bm) ? 3 : bi;
    bi = (s2 == bm) ? 2 : bi;
    bi = (s1 == bm) ? 1 : bi;
    bi = (s0 == bm) ? 0 : bi;
    const int t = k * 8 + s + 1;
    const bool act = (t < len_eff);
    a = act ? (bm + pv[s]) : a;
    const int bie = act ? bi : jj;   // identity backpointer when frozen
    bits |= (uint32_t)bie << (3 * s);
  }
  // path map: exit tag jj at boundary -> 8 decoded tags + entry tag (r4)
  int cur = jj;
  uint32_t dec = 0;
#pragma unroll
  for (int s = 7; s >= 0; --s) {
    const int w = __builtin_amdgcn_ds_bpermute(((g << 3) + cur) << 2, (int)bits);
    const int b3 = (w >> (3 * s)) & 7;
    dec |= (uint32_t)b3 << (3 * s);
    cur = b3;
  }
  if (r < 5) s_map[g * 321 + k * 5 + jj] = dec;
  // ---- fused score: window t in [8k, 8k+7], all off the alpha chain ----
#pragma unroll
  for (int s2 = 0; s2 < 8; ++s2) {
    const int t = k * 8 + s2;
    const int ct = telt(tp, s2);
    const int pt = (s2 == 0) ? tagcar : telt(tp, s2 - 1);
    const float potv = (s2 == 0) ? pvcar : pv[s2 - 1];
    const bool um = (t < len) && (ct == r);     // lanes 5..7 never match
    usum += um ? potv : 0.0f;
    bsum += (um && t >= 1) ? sel5f(trc[0], trc[1], trc[2], trc[3], trc[4], pt) : 0.0f;
  }
  pvcar = pv[7];           // pot[8(k+1)][jj]
  tagcar = telt(tp, 7);    // tag[8k+7]
}

// ---------------- forward: 8 linear-space steps + renorm (r4 exact) --------
__device__ __forceinline__ void fwd_blk(const float (&pv)[8], int k, int len_eff,
                                        const float (&Wc)[KK], float& p, float& Cacc) {
#pragma unroll
  for (int s = 0; s < 8; ++s) {
    const float p0 = swzf<BC0>(p), p1 = swzf<BC1>(p), p2 = swzf<BC2>(p),
                p3 = swzf<BC3>(p), p4 = swzf<BC4>(p);
    const float u  = fmaf(p1, Wc[1], p0 * Wc[0]);
    const float v2 = fmaf(p3, Wc[3], p2 * Wc[2]);
    const float acc = fmaf(p4, Wc[4], u + v2);
    const float E = __expf(pv[s]);
    const int t = k * 8 + s + 1;
    const bool act = (t < len_eff);
    p = act ? (acc * E) : p;
  }
  float m = p;
  m = fmaxf(m, swzf<X1>(m));
  m = fmaxf(m, swzf<X2>(m));
  m = fmaxf(m, swzf<X4>(m));           // lanes r>=5 hold p=0: never the max
  p *= (1.0f / m);
  Cacc += __logf(m);
}

// ---------------------------------------------------------------------------
// grid: B/8 blocks x 128 threads = 2 waves over the SAME 8 batches:
//   wave 0: Viterbi scan + fused unary/binary score + backtrace + decode
//   wave 1: forward scan -> logZ; ll = s_sc[g] - logZ
// No per-chunk barriers (prefetch stays in flight). Exactly two barriers at
// the end, executed by both waves. Same-CU waves share L1 for the pot stream.
// ---------------------------------------------------------------------------
__launch_bounds__(128)
__global__ void crf_kernel(const float* __restrict__ pot,
                           const float* __restrict__ trans,
                           const int* __restrict__ lens,
                           const int* __restrict__ tags,
                           float* __restrict__ out,
                           int B, int T) {
  __shared__ uint32_t s_map[8 * 321];    // [g][k][j] at g*321 + k*5 + j
  __shared__ uint32_t s_chosen[8 * 65];  // packed decoded tags per 8-step block
  __shared__ float s_sc[8];              // per-batch unary+binary (V -> F)
  const int tid = threadIdx.x;
  const int wave = tid >> 6;
  const int lane = tid & 63;
  const int g = lane >> 3, r = lane & 7;
  const int jj = (r < 5) ? r : 4;
  const int b = blockIdx.x * 8 + g;
  const int len = lens[b];
  const int len_eff = (r < 5) ? len : 0;
  const float* __restrict__ prow = pot + (size_t)b * (T * KK);
  const float* __restrict__ colp = prow + jj;

  int ml = len;
  ml = max(ml, __shfl_xor(ml, 8));
  ml = max(ml, __shfl_xor(ml, 16));
  ml = max(ml, __shfl_xor(ml, 32));
  const int nblk = (ml + 7) >> 3;        // wave-uniform (same in both waves)

  int last = 0;
  float logZ = 0.0f;

  if (wave == 0) {
    // ========================= Viterbi + score =========================
    float trc[KK];
#pragma unroll
    for (int i = 0; i < KK; ++i) trc[i] = trans[i * KK + jj];
    float a = (r < 5) ? prow[jj] : -3.0e38f;
    float usum = 0.0f, bsum = 0.0f;
    float pvcar = prow[jj];              // pot[0][jj]; masked by (ct==r)
    int tagcar = 0;                      // unused at t=0 (binary starts t=1)
    const int* __restrict__ tg = tags + (size_t)b * T;

    float pA[8], pB[8], pC[8];
    int4 TA[2], TB[2], TC[2];
    loadCol(pA, colp, 0);               loadTag(TA, tg, 0);
    loadCol(pB, colp, min(1, nblk - 1)); loadTag(TB, tg, min(1, nblk - 1));
    loadCol(pC, colp, min(2, nblk - 1)); loadTag(TC, tg, min(2, nblk - 1));
    int blk = 0;
    while (true) {
      vit_map_block(pA, TA, blk, len, len_eff, trc, a, pvcar, tagcar, usum, bsum, jj, g, r, s_map);
      if (++blk == nblk) break;
      loadCol(pA, colp, min(blk + 2, nblk - 1)); loadTag(TA, tg, min(blk + 2, nblk - 1));
      vit_map_block(pB, TB, blk, len, len_eff, trc, a, pvcar, tagcar, usum, bsum, jj, g, r, s_map);
      if (++blk == nblk) break;
      loadCol(pB, colp, min(blk + 2, nblk - 1)); loadTag(TB, tg, min(blk + 2, nblk - 1));
      vit_map_block(pC, TC, blk, len, len_eff, trc, a, pvcar, tagcar, usum, bsum, jj, g, r, s_map);
      if (++blk == nblk) break;
      loadCol(pC, colp, min(blk + 2, nblk - 1)); loadTag(TC, tg, min(blk + 2, nblk - 1));
    }
    // score reduce over the 8-lane group; stash for the F wave
    float sc = usum + bsum;
    sc += swzf<X1>(sc);
    sc += swzf<X2>(sc);
    sc += swzf<X4>(sc);
    if (r == 0) s_sc[g] = sc;
    // final argmax (first-max) over lanes r<5
    float bm = a;
    bm = fmaxf(bm, swzf<X1>(bm));
    bm = fmaxf(bm, swzf<X2>(bm));
    bm = fmaxf(bm, swzf<X4>(bm));
    int cand = (r < 5 && a == bm) ? r : 7;
    cand = min(cand, swzi<X1>(cand));
    cand = min(cand, swzi<X2>(cand));
    cand = min(cand, swzi<X4>(cand));
    last = cand;
  } else {
    // ========================= forward =========================
    float Wc[KK];
#pragma unroll
    for (int i = 0; i < KK; ++i) Wc[i] = __expf(trans[i * KK + jj]);
    float p = (r < 5) ? __expf(prow[jj]) : 0.0f;
    float Cacc = 0.0f;
    float pA[8], pB[8], pC[8];
    loadCol(pA, colp, 0);
    loadCol(pB, colp, min(1, nblk - 1));
    loadCol(pC, colp, min(2, nblk - 1));
    int blk = 0;
    while (true) {
      fwd_blk(pA, blk, len_eff, Wc, p, Cacc);
      if (++blk == nblk) break;
      loadCol(pA, colp, min(blk + 2, nblk - 1));
      fwd_blk(pB, blk, len_eff, Wc, p, Cacc);
      if (++blk == nblk) break;
      loadCol(pB, colp, min(blk + 2, nblk - 1));
      fwd_blk(pC, blk, len_eff, Wc, p, Cacc);
      if (++blk == nblk) break;
      loadCol(pC, colp, min(blk + 2, nblk - 1));
    }
    float ps = p;
    ps += swzf<X1>(ps);
    ps += swzf<X2>(ps);
    ps += swzf<X4>(ps);                  // lanes r>=5 contribute 0
    logZ = Cacc + __logf(ps);
  }

  __syncthreads();   // barrier 1: s_sc + s_map complete

  if (wave == 0) {
    // ============ post-scan backtrace: lane r==0 per group ============
    if (r == 0) {
      int tag = last;
      uint32_t acc = (uint32_t)last << (3 * ((len - 1) & 7));
      int kcur = (len - 1) >> 3;
      const uint32_t* __restrict__ bb = s_map + g * 321;
      for (int k2 = nblk - 1; k2 >= 0; --k2) {
        // walk whole blocks via the path map (entry tag = word & 7)
        if (k2 < kcur) {
          const uint32_t w = bb[k2 * 5 + tag];
          s_chosen[g * 65 + k2] = w;
          tag = (int)(w & 7u);
        } else if (k2 == kcur) {
          // partial top block: positions (len-1)&7 - 1 down to 0 via map compose
          const uint32_t w = bb[k2 * 5 + tag];
          // decoded positions below len-1 inside this block follow the chosen
          // path map restricted to the chain ending at slot ((len-1)&7):
          // reconstruct by walking w from slot (len-1)&7 - but w already IS the
          // full-block decode for exit tag `tag` at slot 7. For the top block we
          // must only keep slots < (len-1)&7 consistent with the chain from
          // position len-1. Walk bits directly: w gives tag at each slot for
          // exit at slot7; instead recompose: take path ending at our `tag` at
          // slot sl=(len-1)&7 by walking the per-slot entries of w' where w' is
          // the map for exit tag that PASSES through (sl, tag). Since the map
          // rows are built per exit tag, select the row whose slot sl equals tag.
          uint32_t best = acc;
          const int sl = (len - 1) & 7;
#pragma unroll
          for (int cnd = 0; cnd < 5; ++cnd) {
            const uint32_t wr = bb[k2 * 5 + cnd];
            if (((int)((wr >> (3 * sl)) & 7u)) == tag) {
              // keep slots 0..sl-1 from wr, slot sl = tag, upper = 0
              const uint32_t mask = (sl > 0) ? ((1u << (3 * sl)) - 1u) : 0u;
              best = (wr & mask) | ((uint32_t)tag << (3 * sl));
            }
          }
          s_chosen[g * 65 + k2] = best;
          tag = (int)(best & 7u);
        }
      }
    }
  } else {
    if (r == 0) out[(size_t)B * T + b] = s_sc[g] - logZ;
  }

  __syncthreads();   // barrier 2: s_chosen complete

  if (wave == 0) {
    // ============ coalesced decoded write (all V lanes) ============
    float* __restrict__ orow = out + (size_t)b * T;
#pragma unroll
    for (int kk = 0; kk < 8; ++kk) {
      const int k2 = kk * 8 + r;
      const uint32_t w = s_chosen[g * 65 + k2];
      const int base = k2 * 8;
      float f[8];
#pragma unroll
      for (int pI = 0; pI < 8; ++pI)
        f[pI] = (base + pI < len) ? (float)((w >> (3 * pI)) & 7u) : 0.0f;
      *(float4*)(orow + base)     = make_float4(f[0], f[1], f[2], f[3]);
      *(float4*)(orow + base + 4) = make_float4(f[4], f[5], f[6], f[7]);
    }
  }
}

// ---------------------------------------------------------------------------
extern "C" void kernel_launch(void* const* d_in, const int* in_sizes, int n_in,
                              void* d_out, int out_size, void* d_ws, size_t ws_size,
                              hipStream_t stream) {
  const float* pot   = (const float*)d_in[0];
  const float* trans = (const float*)d_in[1];
  const int*   lens  = (const int*)d_in[2];
  const int*   tags  = (const int*)d_in[3];
  float* out = (float*)d_out;

  const int B = in_sizes[2];
  const int T = in_sizes[3] / B;   // 512

  crf_kernel<<<B / 8, 128, 0, stream>>>(pot, trans, lens, tags, out, B, T);
}

// Round 12
// 88.979 us; speedup vs baseline: 2.0297x; 1.3631x over previous
//
#include <hip/hip_runtime.h>
#include <stdint.h>

#define KK 5
#define TT 512

// ---- cross-lane helpers (8-lane groups; 8 | 32 so groups never straddle the
// ds_swizzle 32-lane boundary) ----
template<int P> __device__ __forceinline__ float swzf(float v) {
  return __int_as_float(__builtin_amdgcn_ds_swizzle(__float_as_int(v), P));
}
template<int P> __device__ __forceinline__ int swzi(int v) {
  return __builtin_amdgcn_ds_swizzle(v, P);
}
// broadcast lane (group*8 + i): offset = (i<<5) | 0x18
#define BC0 0x018
#define BC1 0x038
#define BC2 0x058
#define BC3 0x078
#define BC4 0x098
// xor-butterfly within 8-lane group: offset = (m<<10) | 0x1F
#define X1 0x041F
#define X2 0x081F
#define X4 0x101F

__device__ __forceinline__ float sel5f(float v0,float v1,float v2,float v3,float v4,int ct){
  float u=v0; u=(ct==1)?v1:u; u=(ct==2)?v2:u; u=(ct==3)?v3:u; u=(ct==4)?v4:u; return u;
}
__device__ __forceinline__ uint32_t sel5u(uint32_t w0,uint32_t w1,uint32_t w2,uint32_t w3,uint32_t w4,int ct){
  uint32_t u=w0; u=(ct==1)?w1:u; u=(ct==2)?w2:u; u=(ct==3)?w3:u; u=(ct==4)?w4:u; return u;
}
__device__ __forceinline__ int telt(const int4 (&tp)[2], int s) {   // s compile-time
  const int4 v = (s < 4) ? tp[0] : tp[1];
  const int m = s & 3;
  return m == 0 ? v.x : (m == 1 ? v.y : (m == 2 ? v.z : v.w));
}

// load one 8-step column block: element t for t = 8k+1 .. 8k+8 (clamped)
__device__ __forceinline__ void loadCol(float (&d)[8], const float* __restrict__ colp, int k) {
  const int t0 = k * 8 + 1;
  if (k < TT / 8 - 1) {
#pragma unroll
    for (int s = 0; s < 8; ++s) d[s] = colp[(t0 + s) * KK];
  } else {
#pragma unroll
    for (int s = 0; s < 8; ++s) d[s] = colp[min(t0 + s, TT - 1) * KK];
  }
}
// aligned tag window [8k, 8k+7]
__device__ __forceinline__ void loadTag(int4 (&tp)[2], const int* __restrict__ tg, int k) {
  tp[0] = *(const int4*)(tg + 8 * k);
  tp[1] = *(const int4*)(tg + 8 * k + 4);
}

// ---------------- Viterbi: 8 scan steps + path map (r4 semantics) ----------
// Delta 1: map walk = 5 INDEPENDENT bpermute gathers + in-register compose
// (was 8 serially-dependent bpermutes).
__device__ __forceinline__ void vit_map_block(const float (&pv)[8], int k, int len_eff,
                                              const float (&trc)[KK], float& a,
                                              int jj, int g, int r,
                                              uint32_t* __restrict__ s_map) {
  uint32_t bits = 0;
#pragma unroll
  for (int s = 0; s < 8; ++s) {
    const float av0 = swzf<BC0>(a), av1 = swzf<BC1>(a), av2 = swzf<BC2>(a),
                av3 = swzf<BC3>(a), av4 = swzf<BC4>(a);
    const float s0 = av0 + trc[0], s1 = av1 + trc[1], s2 = av2 + trc[2],
                s3 = av3 + trc[3], s4 = av4 + trc[4];
    const float bm = fmaxf(fmaxf(fmaxf(s0, s1), fmaxf(s2, s3)), s4);
    int bi = 4;                      // first-max tie-break == jnp.argmax
    bi = (s3 == bm) ? 3 : bi;
    bi = (s2 == bm) ? 2 : bi;
    bi = (s1 == bm) ? 1 : bi;
    bi = (s0 == bm) ? 0 : bi;
    const int t = k * 8 + s + 1;
    const bool act = (t < len_eff);
    a = act ? (bm + pv[s]) : a;
    const int bie = act ? bi : jj;   // identity backpointer when frozen
    bits |= (uint32_t)bie << (3 * s);
  }
  // gather the 5 tag-columns' bit words (independent bpermutes, one round)
  const uint32_t w0 = (uint32_t)__builtin_amdgcn_ds_bpermute(((g << 3) + 0) << 2, (int)bits);
  const uint32_t w1 = (uint32_t)__builtin_amdgcn_ds_bpermute(((g << 3) + 1) << 2, (int)bits);
  const uint32_t w2 = (uint32_t)__builtin_amdgcn_ds_bpermute(((g << 3) + 2) << 2, (int)bits);
  const uint32_t w3 = (uint32_t)__builtin_amdgcn_ds_bpermute(((g << 3) + 3) << 2, (int)bits);
  const uint32_t w4 = (uint32_t)__builtin_amdgcn_ds_bpermute(((g << 3) + 4) << 2, (int)bits);
  // in-register path map: exit tag jj -> 8 decoded tags (entry tag = dec & 7)
  int cur = jj;
  uint32_t dec = 0;
#pragma unroll
  for (int s = 7; s >= 0; --s) {
    const uint32_t w = sel5u(w0, w1, w2, w3, w4, cur);
    const int b3 = (int)((w >> (3 * s)) & 7u);
    dec |= (uint32_t)b3 << (3 * s);
    cur = b3;
  }
  if (r < 5) s_map[g * 321 + k * 5 + jj] = dec;
}

// ---------------- forward: 8 linear-space steps + fused score + renorm -----
// Delta 2: unary/binary scoring fused via (ct==r) masked adds; no gathers.
__device__ __forceinline__ void fwd_blk(const float (&pv)[8], const int4 (&tp)[2],
                                        int k, int len, int len_eff,
                                        const float (&Wc)[KK], const float (&trcR)[KK],
                                        float& p, float& Cacc,
                                        float& pvcar, int& tagcar,
                                        float& usum, float& bsum, int r) {
#pragma unroll
  for (int s = 0; s < 8; ++s) {
    const float p0 = swzf<BC0>(p), p1 = swzf<BC1>(p), p2 = swzf<BC2>(p),
                p3 = swzf<BC3>(p), p4 = swzf<BC4>(p);
    const float u  = fmaf(p1, Wc[1], p0 * Wc[0]);
    const float v2 = fmaf(p3, Wc[3], p2 * Wc[2]);
    const float acc = fmaf(p4, Wc[4], u + v2);
    const float E = __expf(pv[s]);
    const int t = k * 8 + s + 1;
    const bool act = (t < len_eff);
    p = act ? (acc * E) : p;
  }
  // fused score over window t in [8k, 8k+7] (off the p chain)
#pragma unroll
  for (int s2 = 0; s2 < 8; ++s2) {
    const int t = k * 8 + s2;
    const int ct = telt(tp, s2);
    const int pt = (s2 == 0) ? tagcar : telt(tp, s2 - 1);
    const float potv = (s2 == 0) ? pvcar : pv[s2 - 1];
    const bool um = (t < len) && (ct == r);        // lanes 5..7 never match
    usum += um ? potv : 0.0f;
    bsum += (um && t >= 1) ? sel5f(trcR[0], trcR[1], trcR[2], trcR[3], trcR[4], pt) : 0.0f;
  }
  pvcar = pv[7];          // pot[8(k+1)][jj]
  tagcar = telt(tp, 7);   // tag[8k+7]
  // renorm once per block (r4 exact)
  float m = p;
  m = fmaxf(m, swzf<X1>(m));
  m = fmaxf(m, swzf<X2>(m));
  m = fmaxf(m, swzf<X4>(m));           // lanes r>=5 hold p=0: never the max
  p *= (1.0f / m);
  Cacc += __logf(m);
}

// ---------------------------------------------------------------------------
// grid: 2*(B/8) blocks x 64 threads (1 wave). 8 batches/wave, 8 lanes/batch
// (5 compute tags). role via (blockIdx>>3)&1; blocks u and u+8 share batches
// and XCD. No barriers anywhere.
// ---------------------------------------------------------------------------
__launch_bounds__(64)
__global__ void crf_kernel(const float* __restrict__ pot,
                           const float* __restrict__ trans,
                           const int* __restrict__ lens,
                           const int* __restrict__ tags,
                           float* __restrict__ out,
                           int B, int T) {
  __shared__ uint32_t s_map[8 * 321];   // [g][k][j], stride 321 breaks bank alias
  __shared__ uint32_t s_chosen[8 * 65];
  const int lane = threadIdx.x;
  const int g = lane >> 3, r = lane & 7;
  const int jj = (r < 5) ? r : 4;
  const unsigned u = blockIdx.x;
  const int role = (u >> 3) & 1;
  const int idx = (int)((u & 7u) | ((u >> 4) << 3));
  const int b = idx * 8 + g;
  const int len = lens[b];
  const int len_eff = (r < 5) ? len : 0;
  const float* __restrict__ prow = pot + (size_t)b * (T * KK);
  const float* __restrict__ colp = prow + jj;

  int ml = len;
  ml = max(ml, __shfl_xor(ml, 8));
  ml = max(ml, __shfl_xor(ml, 16));
  ml = max(ml, __shfl_xor(ml, 32));
  const int nblk = (ml + 7) >> 3;       // wave-uniform

  if (role == 0) {
    // ========================= Viterbi (r4 exact + Delta 1) =========================
    float trc[KK];
#pragma unroll
    for (int i = 0; i < KK; ++i) trc[i] = trans[i * KK + jj];
    float a = (r < 5) ? prow[jj] : -3.0e38f;

    float pA[8], pB[8], pC[8];
    loadCol(pA, colp, 0);
    loadCol(pB, colp, min(1, nblk - 1));
    loadCol(pC, colp, min(2, nblk - 1));
    int blk = 0;
    while (true) {
      vit_map_block(pA, blk, len_eff, trc, a, jj, g, r, s_map);
      if (++blk == nblk) break;
      loadCol(pA, colp, min(blk + 2, nblk - 1));
      vit_map_block(pB, blk, len_eff, trc, a, jj, g, r, s_map);
      if (++blk == nblk) break;
      loadCol(pB, colp, min(blk + 2, nblk - 1));
      vit_map_block(pC, blk, len_eff, trc, a, jj, g, r, s_map);
      if (++blk == nblk) break;
      loadCol(pC, colp, min(blk + 2, nblk - 1));
    }
    // final argmax (first-max) over lanes r<5 of each group
    float bm = a;
    bm = fmaxf(bm, swzf<X1>(bm));
    bm = fmaxf(bm, swzf<X2>(bm));
    bm = fmaxf(bm, swzf<X4>(bm));
    int cand = (r < 5 && a == bm) ? r : 7;
    cand = min(cand, swzi<X1>(cand));
    cand = min(cand, swzi<X2>(cand));
    cand = min(cand, swzi<X4>(cand));
    const int last = cand;

    // backtrace via path maps (r4 exact)
    if (r == 0) {
      int tag = last;
      for (int k2 = nblk - 1; k2 >= 0; --k2) {
        const uint32_t w = s_map[g * 321 + k2 * 5 + tag];
        s_chosen[g * 65 + k2] = w;
        tag = (int)(w & 7u);
      }
    }

    // coalesced decoded write (r4 exact)
    float* __restrict__ orow = out + (size_t)b * T;
#pragma unroll
    for (int kk = 0; kk < 8; ++kk) {
      const int k2 = kk * 8 + r;
      const uint32_t w = s_chosen[g * 65 + k2];
      const int base = k2 * 8;
      float f[8];
#pragma unroll
      for (int pI = 0; pI < 8; ++pI)
        f[pI] = (base + pI < len) ? (float)((w >> (3 * pI)) & 7u) : 0.0f;
      *(float4*)(orow + base)     = make_float4(f[0], f[1], f[2], f[3]);
      *(float4*)(orow + base + 4) = make_float4(f[4], f[5], f[6], f[7]);
    }

  } else {
    // ==================== forward + fused score (Delta 2) ====================
    float Wc[KK], trcR[KK];
#pragma unroll
    for (int i = 0; i < KK; ++i) {
      trcR[i] = trans[i * KK + jj];
      Wc[i] = __expf(trcR[i]);
    }
    const float pj0 = prow[jj];
    float p = (r < 5) ? __expf(pj0) : 0.0f;
    float Cacc = 0.0f;
    float usum = 0.0f, bsum = 0.0f;
    float pvcar = pj0;                   // pot[0][jj]
    int tagcar = 0;                      // unused at t=0 (binary starts t=1)
    const int* __restrict__ tg = tags + (size_t)b * T;

    float pA[8], pB[8], pC[8];
    int4 TA[2], TB[2], TC[2];
    loadCol(pA, colp, 0);                loadTag(TA, tg, 0);
    loadCol(pB, colp, min(1, nblk - 1)); loadTag(TB, tg, min(1, nblk - 1));
    loadCol(pC, colp, min(2, nblk - 1)); loadTag(TC, tg, min(2, nblk - 1));
    int blk = 0;
    while (true) {
      fwd_blk(pA, TA, blk, len, len_eff, Wc, trcR, p, Cacc, pvcar, tagcar, usum, bsum, r);
      if (++blk == nblk) break;
      loadCol(pA, colp, min(blk + 2, nblk - 1)); loadTag(TA, tg, min(blk + 2, nblk - 1));
      fwd_blk(pB, TB, blk, len, len_eff, Wc, trcR, p, Cacc, pvcar, tagcar, usum, bsum, r);
      if (++blk == nblk) break;
      loadCol(pB, colp, min(blk + 2, nblk - 1)); loadTag(TB, tg, min(blk + 2, nblk - 1));
      fwd_blk(pC, TC, blk, len, len_eff, Wc, trcR, p, Cacc, pvcar, tagcar, usum, bsum, r);
      if (++blk == nblk) break;
      loadCol(pC, colp, min(blk + 2, nblk - 1)); loadTag(TC, tg, min(blk + 2, nblk - 1));
    }
    // group totals
    float sc = usum + bsum;
    sc += swzf<X1>(sc);
    sc += swzf<X2>(sc);
    sc += swzf<X4>(sc);
    float ps = p;
    ps += swzf<X1>(ps);
    ps += swzf<X2>(ps);
    ps += swzf<X4>(ps);                  // lanes r>=5 contribute 0
    const float logZ = Cacc + __logf(ps);
    if (r == 0) out[(size_t)B * T + b] = sc - logZ;
  }
}

// ---------------------------------------------------------------------------
extern "C" void kernel_launch(void* const* d_in, const int* in_sizes, int n_in,
                              void* d_out, int out_size, void* d_ws, size_t ws_size,
                              hipStream_t stream) {
  const float* pot   = (const float*)d_in[0];
  const float* trans = (const float*)d_in[1];
  const int*   lens  = (const int*)d_in[2];
  const int*   tags  = (const int*)d_in[3];
  float* out = (float*)d_out;

  const int B = in_sizes[2];
  const int T = in_sizes[3] / B;   // 512

  const int nblocks = 2 * (B / 8);  // 2048
  crf_kernel<<<nblocks, 64, 0, stream>>>(pot, trans, lens, tags, out, B, T);
}